// Round 13
// baseline (241.958 us; speedup 1.0000x reference)
//
#include <hip/hip_runtime.h>
#include <hip/hip_bf16.h>

// EGCL, MFMA, mixed weight storage + rcp activations + d2a broadcast
// + __launch_bounds__(256,3) for 3 blocks/CU. B=8, N=256, NF=H=128.
// edge_input@ew1 factorized: T0[i] + T1[j] + dist*ew1[256] + adj*ew1[257].
// Per block (one (b,i)): 256 threads = 4 waves, wave = h-QUARTER (32 h),
// covers all 64 j. j-tiles of 64, 4 iters, 4 barriers/tile.
// GEMM1: A = ew2T in VGPRs (32 regs); B = h1 from LDS.
// GEMM2: A = cw1T from LDS (32KB, staged ONCE); B = m from LDS.
// h1/m share one 16KB LDS buffer. {d2,adj} broadcast via d2a[].
// Register audit: 128 arch VGPR + 32 acc AGPR = 160 unified <= 170 budget.

#define BB 8
#define NN 256
#define HD 128
#define JT 64
#define NT (NN/JT)

typedef short bf16x8 __attribute__((ext_vector_type(8)));
typedef float f32x4  __attribute__((ext_vector_type(4)));

__device__ __forceinline__ float sigmoidf_(float x){
    return __builtin_amdgcn_rcpf(1.0f + __expf(-x));
}
__device__ __forceinline__ float siluf_(float x){
    return x * __builtin_amdgcn_rcpf(1.0f + __expf(-x));
}
__device__ __forceinline__ unsigned int cvtpk_bf16(float lo, float hi){
    unsigned int r;
    asm("v_cvt_pk_bf16_f32 %0, %1, %2" : "=v"(r) : "v"(lo), "v"(hi));
    return r;
}
__device__ __forceinline__ unsigned short f2bf(float x){
    unsigned int u = __float_as_uint(x);
    u += 0x7FFF + ((u>>16)&1);
    return (unsigned short)(u>>16);
}
__device__ __forceinline__ float bf2f(unsigned short h){
    return __uint_as_float(((unsigned int)h)<<16);
}

#define MFMA_BF16(d,a,b) d = __builtin_amdgcn_mfma_f32_16x16x32_bf16(a, b, d, 0, 0, 0)

// ---------- prep kernels ----------

__global__ __launch_bounds__(128) void precompute_T(
    const float* __restrict__ nf, const float* __restrict__ ew1,
    unsigned short* __restrict__ T0, unsigned short* __restrict__ T1)
{
    __shared__ float nfs[HD];
    const int bi = blockIdx.x;
    const int h  = threadIdx.x;
    nfs[h] = nf[(size_t)bi*HD + h];
    __syncthreads();
    float a0 = 0.f, a1 = 0.f;
    #pragma unroll 4
    for (int f = 0; f < HD; ++f){
        const float v = nfs[f];
        a0 = fmaf(v, ew1[f*HD + h],      a0);
        a1 = fmaf(v, ew1[(HD+f)*HD + h], a1);
    }
    T0[bi*HD + h] = f2bf(a0);
    T1[bi*HD + h] = f2bf(a1);
}

// wE: plain transposed bf16 ew2T [h][k] (consumed into registers).
// wC: transposed + XOR-swizzled cw1T (consumed by linear LDS copy + swizzled ds_read).
__global__ __launch_bounds__(256) void prep_w(
    const float* __restrict__ ew2, const float* __restrict__ cw1,
    unsigned short* __restrict__ dst)
{
    const int e = blockIdx.x*256 + threadIdx.x;   // 0..32767
    const int m = e >> 14;
    const int rem = e & 16383;
    const int h = rem >> 7, k = rem & 127;
    if (m == 0)
        dst[rem] = f2bf(ew2[k*HD + h]);                                  // plain
    else
        dst[16384 + ((((h<<7) | k) ^ ((h&7)<<3)))] = f2bf(cw1[k*HD + h]); // swizzled
}

// ---------- main kernel ----------

__global__ __launch_bounds__(256, 3) void egcl_main(
    const float* __restrict__ nf,  const float* __restrict__ pos,
    const float* __restrict__ valid, const float* __restrict__ adj,
    const float* __restrict__ ew1,
    const float* __restrict__ cw2,
    const float* __restrict__ nw1, const float* __restrict__ nw2,
    const float* __restrict__ iw,
    const unsigned short* __restrict__ T0u, const unsigned short* __restrict__ T1u,
    const unsigned short* __restrict__ wE,  const unsigned short* __restrict__ wC,
    float* __restrict__ out)
{
    __shared__ unsigned short sW [16384];   // 32KB cw1T [h'][k] swizzled (staged once)
    __shared__ unsigned short sHM[JT*HD];   // 16KB shared: h1 [j][k] then m [j][h]
    __shared__ float gpart[4][JT];
    __shared__ float cpart[4][JT];
    __shared__ float2 d2a[JT];              // per-j {d2, adj} broadcast
    __shared__ float msgp[HD];
    __shared__ float red3[3];

    const int tid = threadIdx.x;
    const int bi  = blockIdx.x;
    const int b   = bi >> 8;
    const int wm  = tid >> 6;          // wave = h-quarter 0..3
    const int l   = tid & 63, lr = l & 15, lg = l >> 4;
    const int hp  = tid & 63,  jq = tid >> 6;   // P1 mapping: 2 h x 16 j per thread
    const int hh  = tid & 127, half = tid >> 7; // node-MLP mapping

    // ---- stage cw1T into LDS ONCE (linear copy; data pre-swizzled) ----
    {
        const uint4* g = (const uint4*)wC;
        uint4* s = (uint4*)sW;
        #pragma unroll
        for (int r = 0; r < 8; ++r) s[r*256 + tid] = g[r*256 + tid];
    }

    // ---- ew2T A-fragments into registers ONCE (rows h = wm*32+mt*16+lr) ----
    bf16x8 aE[2][4];
    {
        const unsigned short* pE = wE + (((wm*32 + lr) << 7) + lg*8);
        #pragma unroll
        for (int mt = 0; mt < 2; ++mt)
            #pragma unroll
            for (int kk = 0; kk < 4; ++kk)
                aE[mt][kk] = *(const bf16x8*)(pE + (mt*16 << 7) + kk*32);
    }

    // ---- per-thread P1 constants (scalar, register-neutral) ----
    const float t0a = bf2f(T0u[bi*HD + 2*hp]);
    const float t0b = bf2f(T0u[bi*HD + 2*hp + 1]);
    const float w6a = ew1[256*HD + 2*hp], w6b = ew1[256*HD + 2*hp + 1];
    const float w7a = ew1[257*HD + 2*hp], w7b = ew1[257*HD + 2*hp + 1];
    const float pix = pos[bi*3+0], piy = pos[bi*3+1], piz = pos[bi*3+2];
    const float validi = valid[bi];
    const unsigned short* __restrict__ T1b = T1u + (size_t)(b*NN)*HD;
    const float* __restrict__ posb   = pos + (size_t)(b*NN)*3;
    const float* __restrict__ adjrow = adj + (size_t)bi*NN;

    float msgacc[8];
    #pragma unroll
    for (int s = 0; s < 8; ++s) msgacc[s] = 0.f;
    float pax = 0.f, pay = 0.f, paz = 0.f;   // tid<64 only

    // per-j {d2, adj} phase (tid<64), once per (i,j)
    #define D2A_PHASE(tt)                                          \
        if (tid < JT){                                             \
            const int j_ = (tt)*JT + tid;                          \
            const float dx_ = pix - posb[j_*3+0];                  \
            const float dy_ = piy - posb[j_*3+1];                  \
            const float dz_ = piz - posb[j_*3+2];                  \
            d2a[tid] = make_float2(dx_*dx_ + dy_*dy_ + dz_*dz_,    \
                                   adjrow[j_]);                    \
        }

    // ---- prologue: d2a for tile 0 (barrier also fences sW staging) ----
    D2A_PHASE(0)
    __syncthreads();   // P

    for (int t = 0; t < NT; ++t){
        const int j0 = t*JT;

        // ---- P1: h1 = silu(first-layer preact) -> sHM (bf16, swizzled) ----
        #pragma unroll 2
        for (int r = 0; r < 16; ++r){
            const int jl = jq*16 + r;
            const int j  = j0 + jl;
            const float2 da = d2a[jl];
            const ushort2 t1v = *(const ushort2*)&T1b[(size_t)j*HD + 2*hp];
            const float s0 = siluf_(fmaf(da.y, w7a, fmaf(da.x, w6a, t0a + bf2f(t1v.x))));
            const float s1 = siluf_(fmaf(da.y, w7b, fmaf(da.x, w6b, t0b + bf2f(t1v.y))));
            ((unsigned int*)sHM)[(jl*64 + hp) ^ ((jl&7)<<2)] = cvtpk_bf16(s0, s1);
        }
        __syncthreads();   // A: h1 ready

        // ---- GEMM1: m = silu(ew2T @ h1T); A in regs, B from sHM ----
        f32x4 acc[2][4];
        #pragma unroll
        for (int mt = 0; mt < 2; ++mt)
            #pragma unroll
            for (int nt = 0; nt < 4; ++nt)
                acc[mt][nt] = (f32x4){0.f,0.f,0.f,0.f};
        {
            __builtin_amdgcn_s_setprio(1);
            #pragma unroll
            for (int kk = 0; kk < 4; ++kk){
                const int kb = kk*32 + lg*8;
                bf16x8 bf[4];
                #pragma unroll
                for (int nt = 0; nt < 4; ++nt){
                    const int jb = nt*16 + lr;
                    bf[nt] = *(const bf16x8*)&sHM[((jb<<7) + kb) ^ ((jb&7)<<3)];
                }
                #pragma unroll
                for (int mt = 0; mt < 2; ++mt)
                    #pragma unroll
                    for (int nt = 0; nt < 4; ++nt)
                        MFMA_BF16(acc[mt][nt], aE[mt][kk], bf[nt]);
            }
            __builtin_amdgcn_s_setprio(0);
        }
        __syncthreads();   // B: all waves done reading h1 -> sHM reusable

        // ---- GEMM1 epilogue: silu, gate partials, m -> sHM (overwrite) ----
        {
            float pg[4] = {0.f,0.f,0.f,0.f};
            #pragma unroll
            for (int mt = 0; mt < 2; ++mt){
                const f32x4 iwv = *(const f32x4*)&iw[wm*32 + mt*16 + lg*4];
                #pragma unroll
                for (int nt = 0; nt < 4; ++nt){
                    #pragma unroll
                    for (int i = 0; i < 4; ++i){
                        acc[mt][nt][i] = siluf_(acc[mt][nt][i]);
                        pg[nt] = fmaf(acc[mt][nt][i], iwv[i], pg[nt]);
                    }
                    const int jr = nt*16 + lr;
                    uint2 mv;
                    mv.x = cvtpk_bf16(acc[mt][nt][0], acc[mt][nt][1]);
                    mv.y = cvtpk_bf16(acc[mt][nt][2], acc[mt][nt][3]);
                    *(uint2*)&sHM[((jr<<7) + wm*32 + mt*16 + lg*4) ^ ((jr&7)<<3)] = mv;
                }
            }
            #pragma unroll
            for (int nt = 0; nt < 4; ++nt){
                pg[nt] += __shfl_xor(pg[nt], 16);
                pg[nt] += __shfl_xor(pg[nt], 32);
            }
            if (lg == 0){
                #pragma unroll
                for (int nt = 0; nt < 4; ++nt)
                    gpart[wm][nt*16 + lr] = pg[nt];
            }
        }
        __syncthreads();   // C: m + gpart ready

        // ---- gate (per-thread, redundant) + msg accumulation from live m ----
        #pragma unroll
        for (int nt = 0; nt < 4; ++nt){
            const int jr = nt*16 + lr;
            const float g = sigmoidf_(gpart[0][jr]+gpart[1][jr]+gpart[2][jr]+gpart[3][jr]);
            #pragma unroll
            for (int mt = 0; mt < 2; ++mt)
                #pragma unroll
                for (int i = 0; i < 4; ++i)
                    msgacc[mt*4+i] = fmaf(acc[mt][nt][i], g, msgacc[mt*4+i]);
        }

        // ---- GEMM2: c1 = silu(cw1T @ mT); A from sW, B from sHM ----
        #pragma unroll
        for (int mt = 0; mt < 2; ++mt)
            #pragma unroll
            for (int nt = 0; nt < 4; ++nt)
                acc[mt][nt] = (f32x4){0.f,0.f,0.f,0.f};
        {
            __builtin_amdgcn_s_setprio(1);
            #pragma unroll
            for (int kk = 0; kk < 4; ++kk){
                const int kb = kk*32 + lg*8;
                bf16x8 af[2];
                #pragma unroll
                for (int mt = 0; mt < 2; ++mt){
                    const int hr = wm*32 + mt*16 + lr;
                    af[mt] = *(const bf16x8*)&sW[((hr<<7) + kb) ^ ((hr&7)<<3)];
                }
                bf16x8 bf[4];
                #pragma unroll
                for (int nt = 0; nt < 4; ++nt){
                    const int jb = nt*16 + lr;
                    bf[nt] = *(const bf16x8*)&sHM[((jb<<7) + kb) ^ ((jb&7)<<3)];
                }
                #pragma unroll
                for (int mt = 0; mt < 2; ++mt)
                    #pragma unroll
                    for (int nt = 0; nt < 4; ++nt)
                        MFMA_BF16(acc[mt][nt], af[mt], bf[nt]);
            }
            __builtin_amdgcn_s_setprio(0);
        }
        {
            float pc[4] = {0.f,0.f,0.f,0.f};
            #pragma unroll
            for (int mt = 0; mt < 2; ++mt){
                const f32x4 cwv = *(const f32x4*)&cw2[wm*32 + mt*16 + lg*4];
                #pragma unroll
                for (int nt = 0; nt < 4; ++nt)
                    #pragma unroll
                    for (int i = 0; i < 4; ++i)
                        pc[nt] = fmaf(siluf_(acc[mt][nt][i]), cwv[i], pc[nt]);
            }
            #pragma unroll
            for (int nt = 0; nt < 4; ++nt){
                pc[nt] += __shfl_xor(pc[nt], 16);
                pc[nt] += __shfl_xor(pc[nt], 32);
            }
            if (lg == 0){
                #pragma unroll
                for (int nt = 0; nt < 4; ++nt)
                    cpart[wm][nt*16 + lr] = pc[nt];
            }
        }

        // ---- d2a for next tile (between C and D: fenced both ways) ----
        if (t < NT-1) D2A_PHASE(t+1)
        __syncthreads();   // D: cpart + d2a(t+1) ready; sHM m-reads done

        // ---- pos accumulation (threads 0..63, one j each) ----
        if (tid < JT){
            const float c = cpart[0][tid] + cpart[1][tid] + cpart[2][tid] + cpart[3][tid];
            const int j = j0 + tid;
            const float pjx = posb[j*3+0], pjy = posb[j*3+1], pjz = posb[j*3+2];
            const float dx = pix-pjx, dy = piy-pjy, dz = piz-pjz;
            const float d2 = dx*dx + dy*dy + dz*dz;
            const float nrm = __builtin_amdgcn_sqrtf(d2);
            const float inv = __builtin_amdgcn_rcpf(fmaxf(nrm, 1e-10f));
            const float cd = c * inv;
            pax = fmaf(dx, cd, pax);
            pay = fmaf(dy, cd, pay);
            paz = fmaf(dz, cd, paz);
        }
        // hazards: sHM h1-writes(t+1) vs m-reads(t): fenced by D(t);
        // gpart write(t+1) [after B(t+1)] vs read(t) [after C(t)]: fenced;
        // cpart write(t+1) [after C(t+1)] vs read(t) [after D(t)]: fenced;
        // d2a write(t+1) [C(t)..D(t)] vs P1 reads(t) [before A(t)]: fenced;
        // d2a reads(t+1) [after D(t)]: fenced.
    }

    // ---- finalize msg: reduce over lr (j) lanes; each h owned by one wave ----
    #pragma unroll
    for (int s = 0; s < 8; ++s){
        msgacc[s] += __shfl_xor(msgacc[s], 1);
        msgacc[s] += __shfl_xor(msgacc[s], 2);
        msgacc[s] += __shfl_xor(msgacc[s], 4);
        msgacc[s] += __shfl_xor(msgacc[s], 8);
    }
    if (lr == 0){
        #pragma unroll
        for (int mt = 0; mt < 2; ++mt)
            #pragma unroll
            for (int i = 0; i < 4; ++i)
                msgp[wm*32 + mt*16 + lg*4 + i] = msgacc[mt*4+i];
    }

    // ---- finalize pos: wave-0 reduce ----
    if (wm == 0){
        float sx = pax, sy = pay, sz = paz;
        #pragma unroll
        for (int off = 1; off <= 32; off <<= 1){
            sx += __shfl_xor(sx, off);
            sy += __shfl_xor(sy, off);
            sz += __shfl_xor(sz, off);
        }
        if (l == 0){ red3[0] = sx; red3[1] = sy; red3[2] = sz; }
    }
    __syncthreads();   // msgp + red3 ready; sW reads all done -> alias below

    // ---- node MLP scratch aliases the sW region (sW no longer needed) ----
    float* nbuf = (float*)sW;           // ni[256] | n1l[128] | np2[2][128]
    float* ni   = nbuf;
    float* n1l  = nbuf + 256;
    float* np2  = nbuf + 384;

    const float scale = validi * (1.0f/NN);
    if (tid < HD){
        ni[tid]      = nf[(size_t)bi*HD + tid];
        ni[HD + tid] = msgp[tid] * scale;
    }
    if (tid == 0){
        out[(size_t)bi*3+0] = pix + red3[0]*scale;
        out[(size_t)bi*3+1] = piy + red3[1]*scale;
        out[(size_t)bi*3+2] = piz + red3[2]*scale;
    }
    __syncthreads();

    // ---- node MLP (fp32, K split across halves) ----
    float p1 = 0.f;
    for (int f = 0; f < HD; ++f){
        const int ff = half*HD + f;
        p1 = fmaf(ni[ff], nw1[ff*HD + hh], p1);
    }
    np2[half*HD + hh] = p1;
    __syncthreads();
    if (tid < HD) n1l[tid] = siluf_(np2[tid] + np2[HD + tid]);
    __syncthreads();
    float p2 = 0.f;
    for (int k = 0; k < 64; ++k){
        const int kk2 = half*64 + k;
        p2 = fmaf(n1l[kk2], nw2[kk2*HD + hh], p2);
    }
    np2[half*HD + hh] = p2;
    __syncthreads();
    if (tid < HD){
        out[(size_t)BB*NN*3 + (size_t)bi*HD + tid] =
            nf[(size_t)bi*HD + tid] + np2[tid] + np2[HD + tid];
    }
}

extern "C" void kernel_launch(void* const* d_in, const int* in_sizes, int n_in,
                              void* d_out, int out_size, void* d_ws, size_t ws_size,
                              hipStream_t stream)
{
    const float* nf    = (const float*)d_in[0];
    const float* pos   = (const float*)d_in[1];
    const float* valid = (const float*)d_in[2];
    const float* adj   = (const float*)d_in[3];
    const float* ew1   = (const float*)d_in[4];
    const float* ew2   = (const float*)d_in[5];
    const float* cw1   = (const float*)d_in[6];
    const float* cw2   = (const float*)d_in[7];
    const float* nw1   = (const float*)d_in[8];
    const float* nw2   = (const float*)d_in[9];
    const float* iw    = (const float*)d_in[10];
    float* out = (float*)d_out;

    // ws layout: wE(32KB) | wC(32KB) | T0(512KB) | T1(512KB)
    unsigned short* wE  = (unsigned short*)d_ws;
    unsigned short* wC  = wE + 16384;
    unsigned short* T0u = wC + 16384;
    unsigned short* T1u = T0u + (size_t)BB*NN*HD;

    hipLaunchKernelGGL(prep_w, dim3(128), dim3(256), 0, stream, ew2, cw1, wE);
    hipLaunchKernelGGL(precompute_T, dim3(BB*NN), dim3(HD), 0, stream,
                       nf, ew1, T0u, T1u);
    hipLaunchKernelGGL(egcl_main, dim3(BB*NN), dim3(256), 0, stream,
                       nf, pos, valid, adj, ew1, cw2, nw1, nw2, iw,
                       T0u, T1u, wE, wC, out);
}

// Round 14
// 198.954 us; speedup vs baseline: 1.2161x; 1.2161x over previous
//
#include <hip/hip_runtime.h>
#include <hip/hip_bf16.h>

// EGCL, MFMA, pipelined 3-barrier schedule. B=8, N=256, NF=H=128.
// edge_input@ew1 factorized: T0[i] + T1[j] + dist*ew1[256] + adj*ew1[257].
// Per block (one (b,i)): 256 threads = 4 waves, wave = h-QUARTER (32 h),
// covers all 64 j. j-tiles of 64, 4 iters, 3 barriers/tile (A, C, D).
// GEMM1: A = ew2T in VGPRs (32 regs); B = h1 from sH1.
// GEMM2: A = cw1T from LDS sW (32KB, staged ONCE); B = m from sM (separate).
// Pipeline: D2A(t+1) under GEMM1; gate+msg and P1-compute(t+1) (regs ph[16])
// under GEMM2 (acc2 separate from acc1); after D only P1 writes remain.
// Register budget: ~190 of 256 @ 2 waves/SIMD — no spill (check WRITE_SIZE).

#define BB 8
#define NN 256
#define HD 128
#define JT 64
#define NT (NN/JT)

typedef short bf16x8 __attribute__((ext_vector_type(8)));
typedef float f32x4  __attribute__((ext_vector_type(4)));

__device__ __forceinline__ float sigmoidf_(float x){
    return __builtin_amdgcn_rcpf(1.0f + __expf(-x));
}
__device__ __forceinline__ float siluf_(float x){
    return x * __builtin_amdgcn_rcpf(1.0f + __expf(-x));
}
__device__ __forceinline__ unsigned int cvtpk_bf16(float lo, float hi){
    unsigned int r;
    asm("v_cvt_pk_bf16_f32 %0, %1, %2" : "=v"(r) : "v"(lo), "v"(hi));
    return r;
}
__device__ __forceinline__ unsigned short f2bf(float x){
    unsigned int u = __float_as_uint(x);
    u += 0x7FFF + ((u>>16)&1);
    return (unsigned short)(u>>16);
}
__device__ __forceinline__ float bf2f(unsigned short h){
    return __uint_as_float(((unsigned int)h)<<16);
}

#define MFMA_BF16(d,a,b) d = __builtin_amdgcn_mfma_f32_16x16x32_bf16(a, b, d, 0, 0, 0)

// ---------- prep kernels ----------

__global__ __launch_bounds__(128) void precompute_T(
    const float* __restrict__ nf, const float* __restrict__ ew1,
    unsigned short* __restrict__ T0, unsigned short* __restrict__ T1)
{
    __shared__ float nfs[HD];
    const int bi = blockIdx.x;
    const int h  = threadIdx.x;
    nfs[h] = nf[(size_t)bi*HD + h];
    __syncthreads();
    float a0 = 0.f, a1 = 0.f;
    #pragma unroll 4
    for (int f = 0; f < HD; ++f){
        const float v = nfs[f];
        a0 = fmaf(v, ew1[f*HD + h],      a0);
        a1 = fmaf(v, ew1[(HD+f)*HD + h], a1);
    }
    T0[bi*HD + h] = f2bf(a0);
    T1[bi*HD + h] = f2bf(a1);
}

// wE: plain transposed bf16 ew2T [h][k] (consumed into registers).
// wC: transposed + XOR-swizzled cw1T (consumed by linear LDS copy + swizzled ds_read).
__global__ __launch_bounds__(256) void prep_w(
    const float* __restrict__ ew2, const float* __restrict__ cw1,
    unsigned short* __restrict__ dst)
{
    const int e = blockIdx.x*256 + threadIdx.x;   // 0..32767
    const int m = e >> 14;
    const int rem = e & 16383;
    const int h = rem >> 7, k = rem & 127;
    if (m == 0)
        dst[rem] = f2bf(ew2[k*HD + h]);                                  // plain
    else
        dst[16384 + ((((h<<7) | k) ^ ((h&7)<<3)))] = f2bf(cw1[k*HD + h]); // swizzled
}

// ---------- main kernel ----------

__global__ __launch_bounds__(256) void egcl_main(
    const float* __restrict__ nf,  const float* __restrict__ pos,
    const float* __restrict__ valid, const float* __restrict__ adj,
    const float* __restrict__ ew1,
    const float* __restrict__ cw2,
    const float* __restrict__ nw1, const float* __restrict__ nw2,
    const float* __restrict__ iw,
    const unsigned short* __restrict__ T0u, const unsigned short* __restrict__ T1u,
    const unsigned short* __restrict__ wE,  const unsigned short* __restrict__ wC,
    float* __restrict__ out)
{
    __shared__ unsigned short sW [16384];   // 32KB cw1T [h'][k] swizzled (staged once)
    __shared__ unsigned short sH1[JT*HD];   // 16KB h1 [j][k] swizzled
    __shared__ unsigned short sM [JT*HD];   // 16KB m  [j][h] swizzled
    __shared__ float gpart[4][JT];
    __shared__ float cpart[4][JT];
    __shared__ float2 d2a[2][JT];           // double-buffered per-j {d2, adj}
    __shared__ float msgp[HD];
    __shared__ float red3[3];

    const int tid = threadIdx.x;
    const int bi  = blockIdx.x;
    const int b   = bi >> 8;
    const int wm  = tid >> 6;          // wave = h-quarter 0..3
    const int l   = tid & 63, lr = l & 15, lg = l >> 4;
    const int hp  = tid & 63,  jq = tid >> 6;   // P1 mapping: 2 h x 16 j per thread
    const int hh  = tid & 127, half = tid >> 7; // node-MLP mapping

    // ---- stage cw1T into LDS ONCE (linear copy; data pre-swizzled) ----
    {
        const uint4* g = (const uint4*)wC;
        uint4* s = (uint4*)sW;
        #pragma unroll
        for (int r = 0; r < 8; ++r) s[r*256 + tid] = g[r*256 + tid];
    }

    // ---- ew2T A-fragments into registers ONCE (rows h = wm*32+mt*16+lr) ----
    bf16x8 aE[2][4];
    {
        const unsigned short* pE = wE + (((wm*32 + lr) << 7) + lg*8);
        #pragma unroll
        for (int mt = 0; mt < 2; ++mt)
            #pragma unroll
            for (int kk = 0; kk < 4; ++kk)
                aE[mt][kk] = *(const bf16x8*)(pE + (mt*16 << 7) + kk*32);
    }

    // ---- per-thread P1 constants ----
    const float t0a = bf2f(T0u[bi*HD + 2*hp]);
    const float t0b = bf2f(T0u[bi*HD + 2*hp + 1]);
    const float w6a = ew1[256*HD + 2*hp], w6b = ew1[256*HD + 2*hp + 1];
    const float w7a = ew1[257*HD + 2*hp], w7b = ew1[257*HD + 2*hp + 1];
    const float pix = pos[bi*3+0], piy = pos[bi*3+1], piz = pos[bi*3+2];
    const float validi = valid[bi];
    const unsigned short* __restrict__ T1b = T1u + (size_t)(b*NN)*HD;
    const float* __restrict__ posb   = pos + (size_t)(b*NN)*3;
    const float* __restrict__ adjrow = adj + (size_t)bi*NN;

    float msgacc[8];
    #pragma unroll
    for (int s = 0; s < 8; ++s) msgacc[s] = 0.f;
    float pax = 0.f, pay = 0.f, paz = 0.f;   // tid<64 only

    // per-j {d2, adj} phase (tid<64 = wave 0)
    #define D2A_PHASE(tt, buf)                                     \
        if (tid < JT){                                             \
            const int j_ = (tt)*JT + tid;                          \
            const float dx_ = pix - posb[j_*3+0];                  \
            const float dy_ = piy - posb[j_*3+1];                  \
            const float dz_ = piz - posb[j_*3+2];                  \
            d2a[buf][tid] = make_float2(dx_*dx_ + dy_*dy_ + dz_*dz_, \
                                        adjrow[j_]);               \
        }

    // P1 compute for tile tt (buffer buf) into regs ph[16]; FULLY unrolled
    #define P1_COMPUTE(tt, buf, ph)                                             \
        _Pragma("unroll")                                                       \
        for (int r = 0; r < 16; ++r){                                           \
            const int jl = jq*16 + r;                                           \
            const float2 da = d2a[buf][jl];                                     \
            const ushort2 t1v = *(const ushort2*)&T1b[(size_t)((tt)*JT + jl)*HD + 2*hp]; \
            const float s0 = siluf_(fmaf(da.y, w7a, fmaf(da.x, w6a, t0a + bf2f(t1v.x)))); \
            const float s1 = siluf_(fmaf(da.y, w7b, fmaf(da.x, w6b, t0b + bf2f(t1v.y)))); \
            ph[r] = cvtpk_bf16(s0, s1);                                         \
        }

    #define P1_WRITE(ph)                                                        \
        _Pragma("unroll")                                                       \
        for (int r = 0; r < 16; ++r){                                           \
            const int jl = jq*16 + r;                                           \
            ((unsigned int*)sH1)[(jl*64 + hp) ^ ((jl&7)<<2)] = ph[r];           \
        }

    unsigned int ph[16];

    // ---- prologue: d2a(0); fence; P1(0) compute+write ----
    D2A_PHASE(0, 0)
    __syncthreads();   // P: d2a[0] ready (also fences sW staging)
    P1_COMPUTE(0, 0, ph)
    P1_WRITE(ph)

    for (int t = 0; t < NT; ++t){
        __syncthreads();   // A: sH1(t) ready

        // ---- d2a(t+1) under GEMM1 (readers fenced by C) ----
        if (t < NT-1) D2A_PHASE(t+1, (t+1)&1)

        // ---- GEMM1: acc1 = ew2T @ h1T; A in regs, B from sH1 ----
        f32x4 acc1[2][4];
        #pragma unroll
        for (int mt = 0; mt < 2; ++mt)
            #pragma unroll
            for (int nt = 0; nt < 4; ++nt)
                acc1[mt][nt] = (f32x4){0.f,0.f,0.f,0.f};
        {
            __builtin_amdgcn_s_setprio(1);
            #pragma unroll
            for (int kk = 0; kk < 4; ++kk){
                const int kb = kk*32 + lg*8;
                bf16x8 bf[4];
                #pragma unroll
                for (int nt = 0; nt < 4; ++nt){
                    const int jb = nt*16 + lr;
                    bf[nt] = *(const bf16x8*)&sH1[((jb<<7) + kb) ^ ((jb&7)<<3)];
                }
                #pragma unroll
                for (int mt = 0; mt < 2; ++mt)
                    #pragma unroll
                    for (int nt = 0; nt < 4; ++nt)
                        MFMA_BF16(acc1[mt][nt], aE[mt][kk], bf[nt]);
            }
            __builtin_amdgcn_s_setprio(0);
        }

        // ---- epi1: silu(acc1), gate partials, m -> sM ----
        {
            float pg[4] = {0.f,0.f,0.f,0.f};
            #pragma unroll
            for (int mt = 0; mt < 2; ++mt){
                const f32x4 iwv = *(const f32x4*)&iw[wm*32 + mt*16 + lg*4];
                #pragma unroll
                for (int nt = 0; nt < 4; ++nt){
                    #pragma unroll
                    for (int i = 0; i < 4; ++i){
                        acc1[mt][nt][i] = siluf_(acc1[mt][nt][i]);
                        pg[nt] = fmaf(acc1[mt][nt][i], iwv[i], pg[nt]);
                    }
                    const int jr = nt*16 + lr;
                    uint2 mv;
                    mv.x = cvtpk_bf16(acc1[mt][nt][0], acc1[mt][nt][1]);
                    mv.y = cvtpk_bf16(acc1[mt][nt][2], acc1[mt][nt][3]);
                    *(uint2*)&sM[((jr<<7) + wm*32 + mt*16 + lg*4) ^ ((jr&7)<<3)] = mv;
                }
            }
            #pragma unroll
            for (int nt = 0; nt < 4; ++nt){
                pg[nt] += __shfl_xor(pg[nt], 16);
                pg[nt] += __shfl_xor(pg[nt], 32);
            }
            if (lg == 0){
                #pragma unroll
                for (int nt = 0; nt < 4; ++nt)
                    gpart[wm][nt*16 + lr] = pg[nt];
            }
        }
        __syncthreads();   // C: sM + gpart + d2a(t+1) ready

        // ---- GEMM2 (acc2): issue first so gate/msg/P1 fill its shadow ----
        f32x4 acc2[2][4];
        #pragma unroll
        for (int mt = 0; mt < 2; ++mt)
            #pragma unroll
            for (int nt = 0; nt < 4; ++nt)
                acc2[mt][nt] = (f32x4){0.f,0.f,0.f,0.f};
        {
            __builtin_amdgcn_s_setprio(1);
            #pragma unroll
            for (int kk = 0; kk < 4; ++kk){
                const int kb = kk*32 + lg*8;
                bf16x8 af[2];
                #pragma unroll
                for (int mt = 0; mt < 2; ++mt){
                    const int hr = wm*32 + mt*16 + lr;
                    af[mt] = *(const bf16x8*)&sW[((hr<<7) + kb) ^ ((hr&7)<<3)];
                }
                bf16x8 bf[4];
                #pragma unroll
                for (int nt = 0; nt < 4; ++nt){
                    const int jb = nt*16 + lr;
                    bf[nt] = *(const bf16x8*)&sM[((jb<<7) + kb) ^ ((jb&7)<<3)];
                }
                #pragma unroll
                for (int mt = 0; mt < 2; ++mt)
                    #pragma unroll
                    for (int nt = 0; nt < 4; ++nt)
                        MFMA_BF16(acc2[mt][nt], af[mt], bf[nt]);
            }
            __builtin_amdgcn_s_setprio(0);
        }

        // ---- gate + msg accumulation from acc1 (GEMM2 shadow) ----
        #pragma unroll
        for (int nt = 0; nt < 4; ++nt){
            const int jr = nt*16 + lr;
            const float g = sigmoidf_(gpart[0][jr]+gpart[1][jr]+gpart[2][jr]+gpart[3][jr]);
            #pragma unroll
            for (int mt = 0; mt < 2; ++mt)
                #pragma unroll
                for (int i = 0; i < 4; ++i)
                    msgacc[mt*4+i] = fmaf(acc1[mt][nt][i], g, msgacc[mt*4+i]);
        }

        // ---- P1 compute for next tile (GEMM2 shadow) ----
        if (t < NT-1) P1_COMPUTE(t+1, (t+1)&1, ph)

        // ---- epi2: coord partials from acc2 ----
        {
            float pc[4] = {0.f,0.f,0.f,0.f};
            #pragma unroll
            for (int mt = 0; mt < 2; ++mt){
                const f32x4 cwv = *(const f32x4*)&cw2[wm*32 + mt*16 + lg*4];
                #pragma unroll
                for (int nt = 0; nt < 4; ++nt)
                    #pragma unroll
                    for (int i = 0; i < 4; ++i)
                        pc[nt] = fmaf(siluf_(acc2[mt][nt][i]), cwv[i], pc[nt]);
            }
            #pragma unroll
            for (int nt = 0; nt < 4; ++nt){
                pc[nt] += __shfl_xor(pc[nt], 16);
                pc[nt] += __shfl_xor(pc[nt], 32);
            }
            if (lg == 0){
                #pragma unroll
                for (int nt = 0; nt < 4; ++nt)
                    cpart[wm][nt*16 + lr] = pc[nt];
            }
        }
        __syncthreads();   // D: cpart ready; all sM/sH1 reads of tile t done

        // ---- P1 writes for next tile ----
        if (t < NT-1) P1_WRITE(ph)

        // ---- pos accumulation (threads 0..63, one j each) ----
        if (tid < JT){
            const float c = cpart[0][tid] + cpart[1][tid] + cpart[2][tid] + cpart[3][tid];
            const int j = t*JT + tid;
            const float pjx = posb[j*3+0], pjy = posb[j*3+1], pjz = posb[j*3+2];
            const float dx = pix-pjx, dy = piy-pjy, dz = piz-pjz;
            const float d2 = dx*dx + dy*dy + dz*dz;
            const float nrm = __builtin_amdgcn_sqrtf(d2);
            const float inv = __builtin_amdgcn_rcpf(fmaxf(nrm, 1e-10f));
            const float cd = c * inv;
            pax = fmaf(dx, cd, pax);
            pay = fmaf(dy, cd, pay);
            paz = fmaf(dz, cd, paz);
        }
        // hazards: sH1 P1_WRITE(t+1) [after D(t)] vs GEMM1(t) reads [before C(t)]: fenced;
        // sM epi1(t+1) writes [after A(t+1)] vs GEMM2(t) reads [before D(t)]: fenced;
        // gpart epi1(t+1) write [after A(t+1)] vs gate(t) read [before D(t)]: fenced;
        // cpart epi2(t+1) write [after C(t+1)] vs pos(t) read [before A(t+1)]: fenced;
        // d2a[nxt] D2A(t+1) write [after A(t)] vs P1_COMPUTE(t-1) read [before D(t-1)]: fenced;
        // d2a[nxt] readers P1_COMPUTE(t+1) [after C(t)]: fenced by C.
    }

    // ---- finalize msg: reduce over lr (j) lanes; each h owned by one wave ----
    #pragma unroll
    for (int s = 0; s < 8; ++s){
        msgacc[s] += __shfl_xor(msgacc[s], 1);
        msgacc[s] += __shfl_xor(msgacc[s], 2);
        msgacc[s] += __shfl_xor(msgacc[s], 4);
        msgacc[s] += __shfl_xor(msgacc[s], 8);
    }
    if (lr == 0){
        #pragma unroll
        for (int mt = 0; mt < 2; ++mt)
            #pragma unroll
            for (int i = 0; i < 4; ++i)
                msgp[wm*32 + mt*16 + lg*4 + i] = msgacc[mt*4+i];
    }

    // ---- finalize pos: wave-0 reduce ----
    if (wm == 0){
        float sx = pax, sy = pay, sz = paz;
        #pragma unroll
        for (int off = 1; off <= 32; off <<= 1){
            sx += __shfl_xor(sx, off);
            sy += __shfl_xor(sy, off);
            sz += __shfl_xor(sz, off);
        }
        if (l == 0){ red3[0] = sx; red3[1] = sy; red3[2] = sz; }
    }
    __syncthreads();   // msgp + red3 ready; sW reads all done -> alias below

    // ---- node MLP scratch aliases the sW region (sW no longer needed) ----
    float* nbuf = (float*)sW;           // ni[256] | n1l[128] | np2[2][128]
    float* ni   = nbuf;
    float* n1l  = nbuf + 256;
    float* np2  = nbuf + 384;

    const float scale = validi * (1.0f/NN);
    if (tid < HD){
        ni[tid]      = nf[(size_t)bi*HD + tid];
        ni[HD + tid] = msgp[tid] * scale;
    }
    if (tid == 0){
        out[(size_t)bi*3+0] = pix + red3[0]*scale;
        out[(size_t)bi*3+1] = piy + red3[1]*scale;
        out[(size_t)bi*3+2] = piz + red3[2]*scale;
    }
    __syncthreads();

    // ---- node MLP (fp32, K split across halves) ----
    float p1 = 0.f;
    for (int f = 0; f < HD; ++f){
        const int ff = half*HD + f;
        p1 = fmaf(ni[ff], nw1[ff*HD + hh], p1);
    }
    np2[half*HD + hh] = p1;
    __syncthreads();
    if (tid < HD) n1l[tid] = siluf_(np2[tid] + np2[HD + tid]);
    __syncthreads();
    float p2 = 0.f;
    for (int k = 0; k < 64; ++k){
        const int kk2 = half*64 + k;
        p2 = fmaf(n1l[kk2], nw2[kk2*HD + hh], p2);
    }
    np2[half*HD + hh] = p2;
    __syncthreads();
    if (tid < HD){
        out[(size_t)BB*NN*3 + (size_t)bi*HD + tid] =
            nf[(size_t)bi*HD + tid] + np2[tid] + np2[HD + tid];
    }
}

extern "C" void kernel_launch(void* const* d_in, const int* in_sizes, int n_in,
                              void* d_out, int out_size, void* d_ws, size_t ws_size,
                              hipStream_t stream)
{
    const float* nf    = (const float*)d_in[0];
    const float* pos   = (const float*)d_in[1];
    const float* valid = (const float*)d_in[2];
    const float* adj   = (const float*)d_in[3];
    const float* ew1   = (const float*)d_in[4];
    const float* ew2   = (const float*)d_in[5];
    const float* cw1   = (const float*)d_in[6];
    const float* cw2   = (const float*)d_in[7];
    const float* nw1   = (const float*)d_in[8];
    const float* nw2   = (const float*)d_in[9];
    const float* iw    = (const float*)d_in[10];
    float* out = (float*)d_out;

    // ws layout: wE(32KB) | wC(32KB) | T0(512KB) | T1(512KB)
    unsigned short* wE  = (unsigned short*)d_ws;
    unsigned short* wC  = wE + 16384;
    unsigned short* T0u = wC + 16384;
    unsigned short* T1u = T0u + (size_t)BB*NN*HD;

    hipLaunchKernelGGL(prep_w, dim3(128), dim3(256), 0, stream, ew2, cw1, wE);
    hipLaunchKernelGGL(precompute_T, dim3(BB*NN), dim3(HD), 0, stream,
                       nf, ew1, T0u, T1u);
    hipLaunchKernelGGL(egcl_main, dim3(BB*NN), dim3(256), 0, stream,
                       nf, pos, valid, adj, ew1, cw2, nw1, nw2, iw,
                       T0u, T1u, wE, wC, out);
}

// Round 15
// 159.055 us; speedup vs baseline: 1.5212x; 1.2509x over previous
//
#include <hip/hip_runtime.h>
#include <hip/hip_bf16.h>

// EGCL, MFMA, 3-barrier schedule (register-neutral vs 150us baseline).
// B=8, N=256, NF=H=128.
// edge_input@ew1 factorized: T0[i] + T1[j] + dist*ew1[256] + adj*ew1[257].
// Per block (one (b,i)): 256 threads = 4 waves, wave = h-QUARTER (32 h),
// covers all 64 j. j-tiles of 64, 4 iters, 3 barriers/tile (A, C, D).
// GEMM1: A = ew2T in VGPRs (32 regs); B = h1 from sH1 (16KB).
// GEMM2: A = cw1T from LDS sW (32KB, staged ONCE); B = m from sM (16KB).
// Separate sH1/sM kills the old barrier B. {d2,adj} double-buffered d2a[],
// computed by ALL 4 waves (16 j each); pos-accum likewise spread 4 ways.
// Register budget: identical live set to the 128-VGPR baseline.

#define BB 8
#define NN 256
#define HD 128
#define JT 64
#define NT (NN/JT)

typedef short bf16x8 __attribute__((ext_vector_type(8)));
typedef float f32x4  __attribute__((ext_vector_type(4)));

__device__ __forceinline__ float sigmoidf_(float x){
    return __builtin_amdgcn_rcpf(1.0f + __expf(-x));
}
__device__ __forceinline__ float siluf_(float x){
    return x * __builtin_amdgcn_rcpf(1.0f + __expf(-x));
}
__device__ __forceinline__ unsigned int cvtpk_bf16(float lo, float hi){
    unsigned int r;
    asm("v_cvt_pk_bf16_f32 %0, %1, %2" : "=v"(r) : "v"(lo), "v"(hi));
    return r;
}
__device__ __forceinline__ unsigned short f2bf(float x){
    unsigned int u = __float_as_uint(x);
    u += 0x7FFF + ((u>>16)&1);
    return (unsigned short)(u>>16);
}
__device__ __forceinline__ float bf2f(unsigned short h){
    return __uint_as_float(((unsigned int)h)<<16);
}

#define MFMA_BF16(d,a,b) d = __builtin_amdgcn_mfma_f32_16x16x32_bf16(a, b, d, 0, 0, 0)

// ---------- prep kernels ----------

__global__ __launch_bounds__(128) void precompute_T(
    const float* __restrict__ nf, const float* __restrict__ ew1,
    unsigned short* __restrict__ T0, unsigned short* __restrict__ T1)
{
    __shared__ float nfs[HD];
    const int bi = blockIdx.x;
    const int h  = threadIdx.x;
    nfs[h] = nf[(size_t)bi*HD + h];
    __syncthreads();
    float a0 = 0.f, a1 = 0.f;
    #pragma unroll 4
    for (int f = 0; f < HD; ++f){
        const float v = nfs[f];
        a0 = fmaf(v, ew1[f*HD + h],      a0);
        a1 = fmaf(v, ew1[(HD+f)*HD + h], a1);
    }
    T0[bi*HD + h] = f2bf(a0);
    T1[bi*HD + h] = f2bf(a1);
}

// wE: plain transposed bf16 ew2T [h][k] (consumed into registers).
// wC: transposed + XOR-swizzled cw1T (consumed by linear LDS copy + swizzled ds_read).
__global__ __launch_bounds__(256) void prep_w(
    const float* __restrict__ ew2, const float* __restrict__ cw1,
    unsigned short* __restrict__ dst)
{
    const int e = blockIdx.x*256 + threadIdx.x;   // 0..32767
    const int m = e >> 14;
    const int rem = e & 16383;
    const int h = rem >> 7, k = rem & 127;
    if (m == 0)
        dst[rem] = f2bf(ew2[k*HD + h]);                                  // plain
    else
        dst[16384 + ((((h<<7) | k) ^ ((h&7)<<3)))] = f2bf(cw1[k*HD + h]); // swizzled
}

// ---------- main kernel ----------

__global__ __launch_bounds__(256) void egcl_main(
    const float* __restrict__ nf,  const float* __restrict__ pos,
    const float* __restrict__ valid, const float* __restrict__ adj,
    const float* __restrict__ ew1,
    const float* __restrict__ cw2,
    const float* __restrict__ nw1, const float* __restrict__ nw2,
    const float* __restrict__ iw,
    const unsigned short* __restrict__ T0u, const unsigned short* __restrict__ T1u,
    const unsigned short* __restrict__ wE,  const unsigned short* __restrict__ wC,
    float* __restrict__ out)
{
    __shared__ unsigned short sW [16384];   // 32KB cw1T [h'][k] swizzled (staged once)
    __shared__ unsigned short sH1[JT*HD];   // 16KB h1 [j][k] swizzled
    __shared__ unsigned short sM [JT*HD];   // 16KB m  [j][h] swizzled
    __shared__ float gpart[4][JT];
    __shared__ float cpart[4][JT];
    __shared__ float2 d2a[2][JT];           // double-buffered per-j {d2, adj}
    __shared__ float msgp[HD];
    __shared__ float red3p[4][3];

    const int tid = threadIdx.x;
    const int bi  = blockIdx.x;
    const int b   = bi >> 8;
    const int wm  = tid >> 6;          // wave = h-quarter 0..3
    const int l   = tid & 63, lr = l & 15, lg = l >> 4;
    const int hp  = tid & 63,  jq = tid >> 6;   // P1 mapping: 2 h x 16 j per thread
    const int hh  = tid & 127, half = tid >> 7; // node-MLP mapping

    // ---- stage cw1T into LDS ONCE (linear copy; data pre-swizzled) ----
    {
        const uint4* g = (const uint4*)wC;
        uint4* s = (uint4*)sW;
        #pragma unroll
        for (int r = 0; r < 8; ++r) s[r*256 + tid] = g[r*256 + tid];
    }

    // ---- ew2T A-fragments into registers ONCE (rows h = wm*32+mt*16+lr) ----
    bf16x8 aE[2][4];
    {
        const unsigned short* pE = wE + (((wm*32 + lr) << 7) + lg*8);
        #pragma unroll
        for (int mt = 0; mt < 2; ++mt)
            #pragma unroll
            for (int kk = 0; kk < 4; ++kk)
                aE[mt][kk] = *(const bf16x8*)(pE + (mt*16 << 7) + kk*32);
    }

    // ---- per-thread P1 constants (scalar, register-neutral) ----
    const float t0a = bf2f(T0u[bi*HD + 2*hp]);
    const float t0b = bf2f(T0u[bi*HD + 2*hp + 1]);
    const float w6a = ew1[256*HD + 2*hp], w6b = ew1[256*HD + 2*hp + 1];
    const float w7a = ew1[257*HD + 2*hp], w7b = ew1[257*HD + 2*hp + 1];
    const float pix = pos[bi*3+0], piy = pos[bi*3+1], piz = pos[bi*3+2];
    const float validi = valid[bi];
    const unsigned short* __restrict__ T1b = T1u + (size_t)(b*NN)*HD;
    const float* __restrict__ posb   = pos + (size_t)(b*NN)*3;
    const float* __restrict__ adjrow = adj + (size_t)bi*NN;

    float msgacc[8];
    #pragma unroll
    for (int s = 0; s < 8; ++s) msgacc[s] = 0.f;
    float pax = 0.f, pay = 0.f, paz = 0.f;   // lanes l<16 of every wave

    // per-j {d2, adj}: ALL 4 waves, wave wm covers j = wm*16 + (0..15)
    #define D2A_PHASE(tt, buf)                                     \
        if (l < 16){                                               \
            const int jl_ = wm*16 + l;                             \
            const int j_  = (tt)*JT + jl_;                         \
            const float dx_ = pix - posb[j_*3+0];                  \
            const float dy_ = piy - posb[j_*3+1];                  \
            const float dz_ = piz - posb[j_*3+2];                  \
            d2a[buf][jl_] = make_float2(dx_*dx_ + dy_*dy_ + dz_*dz_, \
                                        adjrow[j_]);               \
        }

    // ---- prologue: d2a(0) (barrier also fences sW staging) ----
    D2A_PHASE(0, 0)
    __syncthreads();   // P

    for (int t = 0; t < NT; ++t){
        const int j0 = t*JT;

        // ---- P1: h1 = silu(first-layer preact) -> sH1 (bf16, swizzled) ----
        #pragma unroll 2
        for (int r = 0; r < 16; ++r){
            const int jl = jq*16 + r;
            const int j  = j0 + jl;
            const float2 da = d2a[t&1][jl];
            const ushort2 t1v = *(const ushort2*)&T1b[(size_t)j*HD + 2*hp];
            const float s0 = siluf_(fmaf(da.y, w7a, fmaf(da.x, w6a, t0a + bf2f(t1v.x))));
            const float s1 = siluf_(fmaf(da.y, w7b, fmaf(da.x, w6b, t0b + bf2f(t1v.y))));
            ((unsigned int*)sH1)[(jl*64 + hp) ^ ((jl&7)<<2)] = cvtpk_bf16(s0, s1);
        }
        __syncthreads();   // A: sH1 ready

        // ---- GEMM1: acc = ew2T @ h1T; A in regs, B from sH1 ----
        f32x4 acc[2][4];
        #pragma unroll
        for (int mt = 0; mt < 2; ++mt)
            #pragma unroll
            for (int nt = 0; nt < 4; ++nt)
                acc[mt][nt] = (f32x4){0.f,0.f,0.f,0.f};
        {
            __builtin_amdgcn_s_setprio(1);
            #pragma unroll
            for (int kk = 0; kk < 4; ++kk){
                const int kb = kk*32 + lg*8;
                bf16x8 bf[4];
                #pragma unroll
                for (int nt = 0; nt < 4; ++nt){
                    const int jb = nt*16 + lr;
                    bf[nt] = *(const bf16x8*)&sH1[((jb<<7) + kb) ^ ((jb&7)<<3)];
                }
                #pragma unroll
                for (int mt = 0; mt < 2; ++mt)
                    #pragma unroll
                    for (int nt = 0; nt < 4; ++nt)
                        MFMA_BF16(acc[mt][nt], aE[mt][kk], bf[nt]);
            }
            __builtin_amdgcn_s_setprio(0);
        }

        // ---- epi1: silu(acc), gate partials, m -> sM ----
        {
            float pg[4] = {0.f,0.f,0.f,0.f};
            #pragma unroll
            for (int mt = 0; mt < 2; ++mt){
                const f32x4 iwv = *(const f32x4*)&iw[wm*32 + mt*16 + lg*4];
                #pragma unroll
                for (int nt = 0; nt < 4; ++nt){
                    #pragma unroll
                    for (int i = 0; i < 4; ++i){
                        acc[mt][nt][i] = siluf_(acc[mt][nt][i]);
                        pg[nt] = fmaf(acc[mt][nt][i], iwv[i], pg[nt]);
                    }
                    const int jr = nt*16 + lr;
                    uint2 mv;
                    mv.x = cvtpk_bf16(acc[mt][nt][0], acc[mt][nt][1]);
                    mv.y = cvtpk_bf16(acc[mt][nt][2], acc[mt][nt][3]);
                    *(uint2*)&sM[((jr<<7) + wm*32 + mt*16 + lg*4) ^ ((jr&7)<<3)] = mv;
                }
            }
            #pragma unroll
            for (int nt = 0; nt < 4; ++nt){
                pg[nt] += __shfl_xor(pg[nt], 16);
                pg[nt] += __shfl_xor(pg[nt], 32);
            }
            if (lg == 0){
                #pragma unroll
                for (int nt = 0; nt < 4; ++nt)
                    gpart[wm][nt*16 + lr] = pg[nt];
            }
        }
        __syncthreads();   // C: sM + gpart ready

        // ---- gate (per-thread) + msg accumulation from live acc ----
        #pragma unroll
        for (int nt = 0; nt < 4; ++nt){
            const int jr = nt*16 + lr;
            const float g = sigmoidf_(gpart[0][jr]+gpart[1][jr]+gpart[2][jr]+gpart[3][jr]);
            #pragma unroll
            for (int mt = 0; mt < 2; ++mt)
                #pragma unroll
                for (int i = 0; i < 4; ++i)
                    msgacc[mt*4+i] = fmaf(acc[mt][nt][i], g, msgacc[mt*4+i]);
        }

        // ---- GEMM2: c1 = silu(cw1T @ mT); A from sW, B from sM ----
        #pragma unroll
        for (int mt = 0; mt < 2; ++mt)
            #pragma unroll
            for (int nt = 0; nt < 4; ++nt)
                acc[mt][nt] = (f32x4){0.f,0.f,0.f,0.f};
        {
            __builtin_amdgcn_s_setprio(1);
            #pragma unroll
            for (int kk = 0; kk < 4; ++kk){
                const int kb = kk*32 + lg*8;
                bf16x8 af[2];
                #pragma unroll
                for (int mt = 0; mt < 2; ++mt){
                    const int hr = wm*32 + mt*16 + lr;
                    af[mt] = *(const bf16x8*)&sW[((hr<<7) + kb) ^ ((hr&7)<<3)];
                }
                bf16x8 bf[4];
                #pragma unroll
                for (int nt = 0; nt < 4; ++nt){
                    const int jb = nt*16 + lr;
                    bf[nt] = *(const bf16x8*)&sM[((jb<<7) + kb) ^ ((jb&7)<<3)];
                }
                #pragma unroll
                for (int mt = 0; mt < 2; ++mt)
                    #pragma unroll
                    for (int nt = 0; nt < 4; ++nt)
                        MFMA_BF16(acc[mt][nt], af[mt], bf[nt]);
            }
            __builtin_amdgcn_s_setprio(0);
        }
        {
            float pc[4] = {0.f,0.f,0.f,0.f};
            #pragma unroll
            for (int mt = 0; mt < 2; ++mt){
                const f32x4 cwv = *(const f32x4*)&cw2[wm*32 + mt*16 + lg*4];
                #pragma unroll
                for (int nt = 0; nt < 4; ++nt)
                    #pragma unroll
                    for (int i = 0; i < 4; ++i)
                        pc[nt] = fmaf(siluf_(acc[mt][nt][i]), cwv[i], pc[nt]);
            }
            #pragma unroll
            for (int nt = 0; nt < 4; ++nt){
                pc[nt] += __shfl_xor(pc[nt], 16);
                pc[nt] += __shfl_xor(pc[nt], 32);
            }
            if (lg == 0){
                #pragma unroll
                for (int nt = 0; nt < 4; ++nt)
                    cpart[wm][nt*16 + lr] = pc[nt];
            }
        }

        // ---- d2a for next tile (between C and D: fenced both ways) ----
        if (t < NT-1) D2A_PHASE(t+1, (t+1)&1)
        __syncthreads();   // D: cpart + d2a(t+1) ready; sM/sH1 reads done

        // ---- pos accumulation: wave wm handles j = wm*16 + (0..15) ----
        if (l < 16){
            const int jl = wm*16 + l;
            const float c = cpart[0][jl] + cpart[1][jl] + cpart[2][jl] + cpart[3][jl];
            const int j = j0 + jl;
            const float pjx = posb[j*3+0], pjy = posb[j*3+1], pjz = posb[j*3+2];
            const float dx = pix-pjx, dy = piy-pjy, dz = piz-pjz;
            const float d2 = dx*dx + dy*dy + dz*dz;
            const float nrm = __builtin_amdgcn_sqrtf(d2);
            const float inv = __builtin_amdgcn_rcpf(fmaxf(nrm, 1e-10f));
            const float cd = c * inv;
            pax = fmaf(dx, cd, pax);
            pay = fmaf(dy, cd, pay);
            paz = fmaf(dz, cd, paz);
        }
        // hazards: sH1 P1(t+1) writes [after D(t)] vs GEMM1(t) reads [before C(t)]: fenced;
        // sM epi1(t+1) writes [after A(t+1)] vs GEMM2(t) reads [before D(t)]: fenced;
        // gpart epi1(t+1) write [after A(t+1)] vs gate(t) read [before D(t)]: fenced;
        // cpart epi2(t+1) write [after C(t+1)] vs pos(t) read [before A(t+1)]: fenced;
        // d2a[buf] write(t+1) [C(t)..D(t)] vs P1(t+1) reads [after D(t)]: fenced;
        // vs stale readers P1(t-1) [before A(t-1)]: fenced.
    }

    // ---- finalize msg: reduce over lr (j) lanes; each h owned by one wave ----
    #pragma unroll
    for (int s = 0; s < 8; ++s){
        msgacc[s] += __shfl_xor(msgacc[s], 1);
        msgacc[s] += __shfl_xor(msgacc[s], 2);
        msgacc[s] += __shfl_xor(msgacc[s], 4);
        msgacc[s] += __shfl_xor(msgacc[s], 8);
    }
    if (lr == 0){
        #pragma unroll
        for (int mt = 0; mt < 2; ++mt)
            #pragma unroll
            for (int i = 0; i < 4; ++i)
                msgp[wm*32 + mt*16 + lg*4 + i] = msgacc[mt*4+i];
    }

    // ---- finalize pos: each wave reduces its 16 lanes ----
    if (l < 16){
        float sx = pax, sy = pay, sz = paz;
        #pragma unroll
        for (int off = 1; off <= 8; off <<= 1){
            sx += __shfl_xor(sx, off);
            sy += __shfl_xor(sy, off);
            sz += __shfl_xor(sz, off);
        }
        if (l == 0){ red3p[wm][0] = sx; red3p[wm][1] = sy; red3p[wm][2] = sz; }
    }
    __syncthreads();   // msgp + red3p ready; sW reads all done -> alias below

    // ---- node MLP scratch aliases the sW region (sW no longer needed) ----
    float* nbuf = (float*)sW;           // ni[256] | n1l[128] | np2[2][128]
    float* ni   = nbuf;
    float* n1l  = nbuf + 256;
    float* np2  = nbuf + 384;

    const float scale = validi * (1.0f/NN);
    if (tid < HD){
        ni[tid]      = nf[(size_t)bi*HD + tid];
        ni[HD + tid] = msgp[tid] * scale;
    }
    if (tid == 0){
        out[(size_t)bi*3+0] = pix + (red3p[0][0]+red3p[1][0]+red3p[2][0]+red3p[3][0])*scale;
        out[(size_t)bi*3+1] = piy + (red3p[0][1]+red3p[1][1]+red3p[2][1]+red3p[3][1])*scale;
        out[(size_t)bi*3+2] = piz + (red3p[0][2]+red3p[1][2]+red3p[2][2]+red3p[3][2])*scale;
    }
    __syncthreads();

    // ---- node MLP (fp32, K split across halves) ----
    float p1 = 0.f;
    for (int f = 0; f < HD; ++f){
        const int ff = half*HD + f;
        p1 = fmaf(ni[ff], nw1[ff*HD + hh], p1);
    }
    np2[half*HD + hh] = p1;
    __syncthreads();
    if (tid < HD) n1l[tid] = siluf_(np2[tid] + np2[HD + tid]);
    __syncthreads();
    float p2 = 0.f;
    for (int k = 0; k < 64; ++k){
        const int kk2 = half*64 + k;
        p2 = fmaf(n1l[kk2], nw2[kk2*HD + hh], p2);
    }
    np2[half*HD + hh] = p2;
    __syncthreads();
    if (tid < HD){
        out[(size_t)BB*NN*3 + (size_t)bi*HD + tid] =
            nf[(size_t)bi*HD + tid] + np2[tid] + np2[HD + tid];
    }
}

extern "C" void kernel_launch(void* const* d_in, const int* in_sizes, int n_in,
                              void* d_out, int out_size, void* d_ws, size_t ws_size,
                              hipStream_t stream)
{
    const float* nf    = (const float*)d_in[0];
    const float* pos   = (const float*)d_in[1];
    const float* valid = (const float*)d_in[2];
    const float* adj   = (const float*)d_in[3];
    const float* ew1   = (const float*)d_in[4];
    const float* ew2   = (const float*)d_in[5];
    const float* cw1   = (const float*)d_in[6];
    const float* cw2   = (const float*)d_in[7];
    const float* nw1   = (const float*)d_in[8];
    const float* nw2   = (const float*)d_in[9];
    const float* iw    = (const float*)d_in[10];
    float* out = (float*)d_out;

    // ws layout: wE(32KB) | wC(32KB) | T0(512KB) | T1(512KB)
    unsigned short* wE  = (unsigned short*)d_ws;
    unsigned short* wC  = wE + 16384;
    unsigned short* T0u = wC + 16384;
    unsigned short* T1u = T0u + (size_t)BB*NN*HD;

    hipLaunchKernelGGL(prep_w, dim3(128), dim3(256), 0, stream, ew2, cw1, wE);
    hipLaunchKernelGGL(precompute_T, dim3(BB*NN), dim3(HD), 0, stream,
                       nf, ew1, T0u, T1u);
    hipLaunchKernelGGL(egcl_main, dim3(BB*NN), dim3(256), 0, stream,
                       nf, pos, valid, adj, ew1, cw2, nw1, nw2, iw,
                       T0u, T1u, wE, wC, out);
}